// Round 18
// baseline (3814.108 us; speedup 1.0000x reference)
//
#include <hip/hip_runtime.h>
#include <hip/hip_bf16.h>

#define B_ 32
#define T_ 256
#define E_ 300
#define EP_ 320      // padded K for W_ih MFMA (300 -> 320 = 2 kh x 5 kt x 32)
#define H_ 512
#define O_ 10
#define TEAM 32      // blocks per direction = CUs per XCD
#define THR 512      // threads per recurrence block
#define HPB 16       // h indices per block (512/32)
#define NBLK 512     // 2x oversubscribed so teams always fill

typedef __attribute__((ext_vector_type(8))) short bf16x8;
typedef __attribute__((ext_vector_type(4))) float f32x4;

__device__ __forceinline__ float bf2f(unsigned short u) {
  unsigned v = ((unsigned)u) << 16; float f; __builtin_memcpy(&f, &v, 4); return f;
}
__device__ __forceinline__ short f2bf(float x) {   // RNE bf16 (finite inputs)
  unsigned u; __builtin_memcpy(&u, &x, 4);
  unsigned r = u + 0x7fffu + ((u >> 16) & 1u);
  return (short)(r >> 16);
}

// ---------------- kernel 1a: token gather -> x bf16 hi/lo, K padded to 320 --------
__global__ __launch_bounds__(256) void xprep_k(
    const int* __restrict__ tokens, const float* __restrict__ embed,
    unsigned short* __restrict__ xb)   // [2 hilo][T][B][EP]
{
  const int t = blockIdx.x;
  __shared__ int tok_s[B_];
  const int tid = threadIdx.x;
  if (tid < B_) tok_s[tid] = tokens[tid * T_ + t];
  __syncthreads();
  const size_t plane = (size_t)T_ * B_ * EP_;
  unsigned short* hi = xb;
  unsigned short* lo = xb + plane;
  for (int i = tid; i < B_ * E_; i += 256) {
    const int b = i / E_, e = i - b * E_;
    const float v = embed[(size_t)tok_s[b] * E_ + e];
    const short h = f2bf(v);
    const short l = f2bf(v - bf2f((unsigned short)h));
    const size_t o = ((size_t)t * B_ + b) * EP_ + e;
    hi[o] = (unsigned short)h; lo[o] = (unsigned short)l;
  }
  for (int i = tid; i < B_ * (EP_ - E_); i += 256) {   // zero the K pad
    const int b = i / (EP_ - E_), e = E_ + (i - b * (EP_ - E_));
    const size_t o = ((size_t)t * B_ + b) * EP_ + e;
    hi[o] = 0; lo[o] = 0;
  }
}

// ---------------- kernel 1b: W_ih -> bf16 hi/lo planes, K padded ------------------
__global__ __launch_bounds__(320) void wprep_k(
    const float* __restrict__ Wf, const float* __restrict__ Wb,
    unsigned short* __restrict__ wp)   // [2 dir][2 hilo][2048][EP]
{
  const int row = blockIdx.x;          // 0..2047
  const int dir = blockIdx.y;
  const int e   = threadIdx.x;         // 0..319
  const float* __restrict__ W = dir ? Wb : Wf;
  short h = 0, l = 0;
  if (e < E_) {
    const float v = W[(size_t)row * E_ + e];
    h = f2bf(v);
    l = f2bf(v - bf2f((unsigned short)h));
  }
  const size_t hiB = ((size_t)(dir * 2 + 0)) * 2048 * EP_;
  const size_t loB = ((size_t)(dir * 2 + 1)) * 2048 * EP_;
  wp[hiB + (size_t)row * EP_ + e] = (unsigned short)h;
  wp[loB + (size_t)row * EP_ + e] = (unsigned short)l;
}

// ---------------- kernel 2: XCD-local MFMA LSTM recurrence, fused xg --------------
// r15/r16 structure frozen (TEAM=32, election, hot-tag nt-poll + agent backstop,
// full-line publish, drains). NEW: the W_ih@x contribution (formerly xg_mfma_k)
// is computed IN-LOOP by the recurrence blocks during the barrier wait, straight
// into the same MFMA accumulators (identical C layout / k conventions). W_ih
// A-frags preloaded once (40 VGPRs); xb B-frags read from L2 per step. Bias is
// added in fp32 in the cell. xg buffer + kernel + cell xg loads: deleted.
__device__ __forceinline__ float sigm(float x)    { return 1.f / (1.f + __expf(-x)); }
__device__ __forceinline__ float tanhfast(float x){ return 1.f - 2.f / (__expf(2.f * x) + 1.f); }

__global__ __launch_bounds__(THR) void lstm_rec_k(
    const unsigned short* __restrict__ xbuf,   // [2 hilo][T][B][EP]
    const unsigned short* __restrict__ wp,     // [2 dir][2 hilo][2048][EP]
    const float* __restrict__ Whf, const float* __restrict__ Whb,
    const float* __restrict__ bif, const float* __restrict__ bhf,
    const float* __restrict__ bib, const float* __restrict__ bhb,
    unsigned short* __restrict__ ht,   // [dir][s][rank 32][plane 2][512] ushort
    float* __restrict__ pooled,
    unsigned int* __restrict__ tags, unsigned int* __restrict__ elect)
{
  unsigned xcd;
  asm volatile("s_getreg_b32 %0, hwreg(HW_REG_XCC_ID)" : "=s"(xcd));
  xcd &= 7u;

  __shared__ unsigned rank_s;
  if (threadIdx.x == 0)
    rank_s = __hip_atomic_fetch_add(&elect[xcd], 1u, __ATOMIC_RELAXED,
                                    __HIP_MEMORY_SCOPE_AGENT);
  __syncthreads();
  const unsigned rank = rank_s;
  if (xcd > 1u || rank >= TEAM) return;   // block-uniform exit (frees CU)
  const int dir = (int)xcd;

  const float* __restrict__ Wh = dir ? Whb : Whf;   // [2048][512]
  const float* __restrict__ bi = dir ? bib : bif;
  const float* __restrict__ bh = dir ? bhb : bhf;
  const int hs  = (int)rank * HPB;
  const int tid = threadIdx.x;
  const int l   = tid & 63;            // MFMA lane
  const int wid = tid >> 6;            // 8 waves
  const int g   = wid & 3;             // gate (i,f,g,o)
  const int kh  = wid >> 2;            // k-half
  const int hh  = tid & 15, bb = tid >> 4;   // cell-update role (h idx, batch)

  extern __shared__ char lds[];        // [0,64K): h bf16 hi|lo ; [64K,+17408): gp
  float* gp = (float*)(lds + 65536);   // [8 slot][32 b][17] fp32 gate partials

  // ---- W_hh A-frags: 16 rows x 256-k half, bf16 hi/lo (64 VGPRs) ----
  bf16x8 ahi[8], alo[8];
  {
    const int m = l & 15, q = l >> 4;
    const float* wrow = Wh + (size_t)(g * H_ + hs + m) * H_ + kh * 256 + q * 8;
    #pragma unroll
    for (int kt = 0; kt < 8; ++kt) {
      const float* wpr = wrow + kt * 32;
      #pragma unroll
      for (int j = 0; j < 8; ++j) {
        const float w = wpr[j];
        const short hi = f2bf(w);
        ahi[kt][j] = hi;
        alo[kt][j] = f2bf(w - bf2f((unsigned short)hi));
      }
    }
  }
  // ---- W_ih A-frags: 16 rows x 160-k half (5 kt), bf16 hi/lo (40 VGPRs) ----
  bf16x8 xhi[5], xlo[5];
  {
    const int m = l & 15, q = l >> 4;
    const unsigned short* whi =
        wp + ((size_t)(dir * 2 + 0) * 2048 + g * H_ + hs + m) * EP_ + kh * 160 + q * 8;
    const unsigned short* wlo =
        wp + ((size_t)(dir * 2 + 1) * 2048 + g * H_ + hs + m) * EP_ + kh * 160 + q * 8;
    #pragma unroll
    for (int kt = 0; kt < 5; ++kt) {
      xhi[kt] = *(const bf16x8*)(whi + kt * 32);
      xlo[kt] = *(const bf16x8*)(wlo + kt * 32);
    }
  }
  // ---- bias for this thread's cell (4 gates), fp32 ----
  float bsum[4];
  #pragma unroll
  for (int gg2 = 0; gg2 < 4; ++gg2)
    bsum[gg2] = bi[gg2 * H_ + hs + hh] + bh[gg2 * H_ + hs + hh];

  const size_t xplane = (size_t)T_ * B_ * EP_;
  unsigned int* __restrict__ mytags = tags + dir * 32;

  float c_st = 0.f, pm = 0.f;

  for (int s = 0; s < T_; ++s) {
    const int tt = dir ? (T_ - 1 - s) : s;
    // ---- xg contribution: W_ih @ x[tt] into fresh accumulators (independent
    //      of h -> runs while other blocks are still finishing step s-1).
    f32x4 acc0 = {0.f, 0.f, 0.f, 0.f}, acc1 = {0.f, 0.f, 0.f, 0.f};
    {
      const int n0 = l & 15, q = l >> 4;
      const unsigned short* x0p =
          xbuf + ((size_t)tt * B_ + n0     ) * EP_ + kh * 160 + q * 8;
      const unsigned short* x1p =
          xbuf + ((size_t)tt * B_ + n0 + 16) * EP_ + kh * 160 + q * 8;
      #pragma unroll
      for (int kt = 0; kt < 5; ++kt) {
        bf16x8 b0h = *(const bf16x8*)(x0p + kt * 32);
        bf16x8 b0l = *(const bf16x8*)(x0p + xplane + kt * 32);
        bf16x8 b1h = *(const bf16x8*)(x1p + kt * 32);
        bf16x8 b1l = *(const bf16x8*)(x1p + xplane + kt * 32);
        acc0 = __builtin_amdgcn_mfma_f32_16x16x32_bf16(xhi[kt], b0h, acc0, 0, 0, 0);
        acc0 = __builtin_amdgcn_mfma_f32_16x16x32_bf16(xlo[kt], b0h, acc0, 0, 0, 0);
        acc0 = __builtin_amdgcn_mfma_f32_16x16x32_bf16(xhi[kt], b0l, acc0, 0, 0, 0);
        acc1 = __builtin_amdgcn_mfma_f32_16x16x32_bf16(xhi[kt], b1h, acc1, 0, 0, 0);
        acc1 = __builtin_amdgcn_mfma_f32_16x16x32_bf16(xlo[kt], b1h, acc1, 0, 0, 0);
        acc1 = __builtin_amdgcn_mfma_f32_16x16x32_bf16(xhi[kt], b1l, acc1, 0, 0, 0);
      }
    }

    if (s > 0) {
      // wait: 32 lanes poll the HOT tag line (nt); agent backstop after 64.
      if (tid < 64) {
        unsigned v = 0xFFFFFFFFu;
        const unsigned int* tp = mytags + (tid & 31);
        int it = 0;
        do {
          if (tid < 32) {
            if (it < 64) {
              asm volatile("global_load_dword %0, %1, off sc0 nt\n\ts_waitcnt vmcnt(0)"
                           : "=v"(v) : "v"(tp) : "memory");
            } else {
              v = __hip_atomic_load(tp, __ATOMIC_RELAXED, __HIP_MEMORY_SCOPE_AGENT);
            }
          }
          ++it;
        } while (__ballot(v < (unsigned)s) != 0ull && it < (1 << 22));
      }
      __syncthreads();
      // stage h(s-1): 64 KB rank-major linear read, permute into swizzled LDS
      {
        const float4* src = (const float4*)(ht + (size_t)(dir * T_ + (s - 1)) * 32768);
        #pragma unroll
        for (int ii = 0; ii < 8; ++ii) {
          const int i = tid + ii * THR;          // 0..4095
          const float4 v4 = src[i];
          const int rk = i >> 7;                 // rank
          const int f  = i & 127;
          const int pl = f >> 6;                 // plane (hi/lo)
          const int j  = f & 63;                 // float4 within plane
          const int b  = j >> 1;
          const int h0 = (j & 1) * 8;            // first of 8 hh
          const int dst = pl * 32768 +
              ((b * 1024 + (rk * HPB + h0) * 2) ^ ((b & 7) << 4));
          *(float4*)(lds + dst) = v4;
        }
      }
      __syncthreads();
      // W_hh MFMAs accumulate ON TOP of the xg accumulators
      {
        const int n0 = l & 15;
        const int swz = (n0 & 7) << 4;
        const int kb = kh * 512 + (l >> 4) * 16;   // byte offset of lane's k
        #pragma unroll
        for (int kt = 0; kt < 8; ++kt) {
          const int ko = kb + kt * 64;
          const char* p0 = lds + (((n0      ) * 1024 + ko) ^ swz);
          const char* p1 = lds + (((n0 + 16 ) * 1024 + ko) ^ swz);
          bf16x8 b0h = *(const bf16x8*)(p0);
          bf16x8 b0l = *(const bf16x8*)(p0 + 32768);
          bf16x8 b1h = *(const bf16x8*)(p1);
          bf16x8 b1l = *(const bf16x8*)(p1 + 32768);
          acc0 = __builtin_amdgcn_mfma_f32_16x16x32_bf16(ahi[kt], b0h, acc0, 0, 0, 0);
          acc0 = __builtin_amdgcn_mfma_f32_16x16x32_bf16(alo[kt], b0h, acc0, 0, 0, 0);
          acc0 = __builtin_amdgcn_mfma_f32_16x16x32_bf16(ahi[kt], b0l, acc0, 0, 0, 0);
          acc1 = __builtin_amdgcn_mfma_f32_16x16x32_bf16(ahi[kt], b1h, acc1, 0, 0, 0);
          acc1 = __builtin_amdgcn_mfma_f32_16x16x32_bf16(alo[kt], b1h, acc1, 0, 0, 0);
          acc1 = __builtin_amdgcn_mfma_f32_16x16x32_bf16(ahi[kt], b1l, acc1, 0, 0, 0);
        }
      }
    }
    // write gate partials (xg + W_hh): C col=lane&15 (batch), row=(l>>4)*4+r
    {
      const int slot = (kh * 4 + g) * 32;
      const int rowb = (l >> 4) * 4;
      #pragma unroll
      for (int r = 0; r < 4; ++r) {
        gp[(slot + (l & 15)     ) * 17 + rowb + r] = acc0[r];
        gp[(slot + 16 + (l & 15)) * 17 + rowb + r] = acc1[r];
      }
    }
    __syncthreads();

    // ---- cell update for (h = hs+hh, batch bb): fp32 bias, gp carries all ----
    const float Gi = gp[(0 * 32 + bb) * 17 + hh] + gp[(4 * 32 + bb) * 17 + hh] + bsum[0];
    const float Gf = gp[(1 * 32 + bb) * 17 + hh] + gp[(5 * 32 + bb) * 17 + hh] + bsum[1];
    const float Gg = gp[(2 * 32 + bb) * 17 + hh] + gp[(6 * 32 + bb) * 17 + hh] + bsum[2];
    const float Go = gp[(3 * 32 + bb) * 17 + hh] + gp[(7 * 32 + bb) * 17 + hh] + bsum[3];
    c_st = sigm(Gf) * c_st + sigm(Gi) * tanhfast(Gg);
    const float h = sigm(Go) * tanhfast(c_st);
    pm = fmaxf(pm, h);
    // publish h: contiguous rank-major full-line stores (r15-proven)
    {
      const short hi = f2bf(h);
      const short lo = f2bf(h - bf2f((unsigned short)hi));
      unsigned short* region =
          ht + (size_t)(dir * T_ + s) * 32768 + (size_t)rank * 1024;
      region[tid]       = (unsigned short)hi;
      region[512 + tid] = (unsigned short)lo;
    }
    // drain own stores to local L2, block-wide, then arrive: monotonic tag
    asm volatile("s_waitcnt vmcnt(0)" ::: "memory");
    __syncthreads();
    if (tid == 0) {
      unsigned int* tp = mytags + rank;
      unsigned val = (unsigned)(s + 1);
      asm volatile("global_store_dword %0, %1, off\n\ts_waitcnt vmcnt(0)"
                   :: "v"(tp), "v"(val) : "memory");
    }
  }
  pooled[(size_t)bb * 1024 + dir * H_ + hs + hh] = pm;
}

// ---------------- kernel 3: ht v2 -> rnn_out [t][b][dir*512+k] fp32 ---------------
__global__ __launch_bounds__(256) void finalize_k(
    const unsigned short* __restrict__ ht, float* __restrict__ rnn)
{
  const int t = blockIdx.x, dir = blockIdx.y;
  const int s = dir ? (T_ - 1 - t) : t;
  const unsigned short* slab = ht + (size_t)(dir * T_ + s) * 32768;
  const int b = threadIdx.x >> 3, c = threadIdx.x & 7;
  float* __restrict__ dst = rnn + ((size_t)t * B_ + b) * 1024 + dir * H_;
  #pragma unroll
  for (int j = 0; j < 16; ++j) {
    const int k0 = c * 64 + j * 4;                 // 4 consecutive k, same rank
    const int rk = k0 >> 4;
    const unsigned short* rg = slab + rk * 1024 + b * HPB + (k0 & 15);
    float4 o;
    o.x = bf2f(rg[0]) + bf2f(rg[512 + 0]);
    o.y = bf2f(rg[1]) + bf2f(rg[512 + 1]);
    o.z = bf2f(rg[2]) + bf2f(rg[512 + 2]);
    o.w = bf2f(rg[3]) + bf2f(rg[512 + 3]);
    *(float4*)(dst + k0) = o;
  }
}

// ---------------- kernel 4: logits = pooled @ W_out^T + b_out ---------------------
__global__ __launch_bounds__(64) void logits_k(
    const float* __restrict__ pooled, const float* __restrict__ Wout,
    const float* __restrict__ bout, float* __restrict__ out)
{
  const int b = blockIdx.x, lane = threadIdx.x;
  float acc[O_];
  #pragma unroll
  for (int o = 0; o < O_; ++o) acc[o] = 0.f;
  for (int k = lane; k < 2 * H_; k += 64) {
    const float pv = pooled[(size_t)b * 1024 + k];
    #pragma unroll
    for (int o = 0; o < O_; ++o) acc[o] += pv * Wout[(size_t)o * 1024 + k];
  }
  #pragma unroll
  for (int o = 0; o < O_; ++o) {
    float v = acc[o];
    #pragma unroll
    for (int off = 32; off > 0; off >>= 1) v += __shfl_down(v, off);
    if (lane == 0) out[b * O_ + o] = v + bout[o];
  }
}

extern "C" void kernel_launch(void* const* d_in, const int* in_sizes, int n_in,
                              void* d_out, int out_size, void* d_ws, size_t ws_size,
                              hipStream_t stream)
{
  const int*   tokens = (const int*)d_in[0];
  const float* embed  = (const float*)d_in[1];
  const float* Wihf   = (const float*)d_in[2];
  const float* Whhf   = (const float*)d_in[3];
  const float* bihf   = (const float*)d_in[4];
  const float* bhhf   = (const float*)d_in[5];
  const float* Wihb   = (const float*)d_in[6];
  const float* Whhb   = (const float*)d_in[7];
  const float* bihb   = (const float*)d_in[8];
  const float* bhhb   = (const float*)d_in[9];
  const float* Wout   = (const float*)d_in[10];
  const float* bout   = (const float*)d_in[11];
  float* out = (float*)d_out;

  char* ws = (char*)d_ws;
  const size_t XB_BYTES = (size_t)2 * T_ * B_ * EP_ * 2;        // 10,485,760
  const size_t WP_BYTES = (size_t)2 * 2 * 2048 * EP_ * 2;       //  5,242,880
  const size_t HT_BYTES = (size_t)2 * T_ * 32768 * 2;           // 33,554,432
  const size_t PL_BYTES = (size_t)B_ * 1024 * 4;                //    131,072
  const size_t TG_BYTES = 2 * 32 * 4;                           //        256
  const size_t EL_BYTES = 8 * 4;                                //         32
  if (ws_size < XB_BYTES + WP_BYTES + HT_BYTES + PL_BYTES + TG_BYTES + EL_BYTES)
    return;

  unsigned short* xb     = (unsigned short*)ws;
  unsigned short* wpre   = (unsigned short*)(ws + XB_BYTES);
  unsigned short* ht     = (unsigned short*)(ws + XB_BYTES + WP_BYTES);
  float*          pooled = (float*)(ws + XB_BYTES + WP_BYTES + HT_BYTES);
  unsigned int*   tags   = (unsigned int*)(ws + XB_BYTES + WP_BYTES + HT_BYTES + PL_BYTES);
  unsigned int*   elect  = (unsigned int*)(ws + XB_BYTES + WP_BYTES + HT_BYTES + PL_BYTES + TG_BYTES);

  (void)hipMemsetAsync(tags, 0, TG_BYTES + EL_BYTES, stream);

  xprep_k<<<dim3(T_), 256, 0, stream>>>(tokens, embed, xb);
  wprep_k<<<dim3(2048, 2), 320, 0, stream>>>(Wihf, Wihb, wpre);

  // 82,944 B dynamic LDS (64K h + 17,408 gp); 2x82944 > 160 KB -> 1 block/CU.
  const int rec_lds = 82944;
  (void)hipFuncSetAttribute((const void*)lstm_rec_k,
                            hipFuncAttributeMaxDynamicSharedMemorySize, rec_lds);
  lstm_rec_k<<<dim3(NBLK), THR, rec_lds, stream>>>(
      xb, wpre, Whhf, Whhb, bihf, bhhf, bihb, bhhb, ht, pooled, tags, elect);

  finalize_k<<<dim3(T_, 2), 256, 0, stream>>>(ht, out + B_ * O_);
  logits_k<<<dim3(B_), 64, 0, stream>>>(pooled, Wout, bout, out);
}

// Round 19
// 3181.666 us; speedup vs baseline: 1.1988x; 1.1988x over previous
//
#include <hip/hip_runtime.h>
#include <hip/hip_bf16.h>

#define B_ 32
#define T_ 256
#define E_ 300
#define EP_ 320      // padded K for MFMA (300 -> 320)
#define H_ 512
#define O_ 10
#define TEAM 32      // blocks per direction = CUs per XCD
#define THR 512      // threads per recurrence block
#define HPB 16       // h indices per block (512/32)
#define NBLK 512     // 2x oversubscribed so teams always fill
#define TPB 4        // time-steps per xg block (A-fragment reuse)

typedef __attribute__((ext_vector_type(8))) short bf16x8;
typedef __attribute__((ext_vector_type(4))) float f32x4;

__device__ __forceinline__ float bf2f(unsigned short u) {
  unsigned v = ((unsigned)u) << 16; float f; __builtin_memcpy(&f, &v, 4); return f;
}
__device__ __forceinline__ short f2bf(float x) {   // RNE bf16 (finite inputs)
  unsigned u; __builtin_memcpy(&u, &x, 4);
  unsigned r = u + 0x7fffu + ((u >> 16) & 1u);
  return (short)(r >> 16);
}

// ---------------- kernel 1a: token gather -> x bf16 hi/lo, K padded to 320 --------
__global__ __launch_bounds__(256) void xprep_k(
    const int* __restrict__ tokens, const float* __restrict__ embed,
    unsigned short* __restrict__ xb)   // [2 hilo][T][B][EP]
{
  const int t = blockIdx.x;
  __shared__ int tok_s[B_];
  const int tid = threadIdx.x;
  if (tid < B_) tok_s[tid] = tokens[tid * T_ + t];
  __syncthreads();
  const size_t plane = (size_t)T_ * B_ * EP_;
  unsigned short* hi = xb;
  unsigned short* lo = xb + plane;
  for (int i = tid; i < B_ * E_; i += 256) {
    const int b = i / E_, e = i - b * E_;
    const float v = embed[(size_t)tok_s[b] * E_ + e];
    const short h = f2bf(v);
    const short l = f2bf(v - bf2f((unsigned short)h));
    const size_t o = ((size_t)t * B_ + b) * EP_ + e;
    hi[o] = (unsigned short)h; lo[o] = (unsigned short)l;
  }
  for (int i = tid; i < B_ * (EP_ - E_); i += 256) {   // zero the K pad
    const int b = i / (EP_ - E_), e = E_ + (i - b * (EP_ - E_));
    const size_t o = ((size_t)t * B_ + b) * EP_ + e;
    hi[o] = 0; lo[o] = 0;
  }
}

// ---------------- kernel 1b: W_ih -> bf16 hi/lo planes, K padded ------------------
__global__ __launch_bounds__(320) void wprep_k(
    const float* __restrict__ Wf, const float* __restrict__ Wb,
    unsigned short* __restrict__ wp)   // [2 dir][2 hilo][2048][EP]
{
  const int row = blockIdx.x;          // 0..2047
  const int dir = blockIdx.y;
  const int e   = threadIdx.x;         // 0..319
  const float* __restrict__ W = dir ? Wb : Wf;
  short h = 0, l = 0;
  if (e < E_) {
    const float v = W[(size_t)row * E_ + e];
    h = f2bf(v);
    l = f2bf(v - bf2f((unsigned short)h));
  }
  const size_t hiB = ((size_t)(dir * 2 + 0)) * 2048 * EP_;
  const size_t loB = ((size_t)(dir * 2 + 1)) * 2048 * EP_;
  wp[hiB + (size_t)row * EP_ + e] = (unsigned short)h;
  wp[loB + (size_t)row * EP_ + e] = (unsigned short)l;
}

// ---------------- kernel 1c: xg via MFMA, 4 t per block (A-frag reuse) ------------
__global__ __launch_bounds__(256) void xg_mfma_k(
    const unsigned short* __restrict__ wp,   // [2][2][2048][EP]
    const unsigned short* __restrict__ xb,   // [2][T][B][EP]
    const float* __restrict__ bif, const float* __restrict__ bhf,
    const float* __restrict__ bib, const float* __restrict__ bhb,
    __hip_bfloat16* __restrict__ xg)         // [dir][t][2048][B] bf16
{
  const int rt  = blockIdx.x;    // 32 tiles of 64 rows
  const int tg  = blockIdx.y;    // 64 groups of TPB time-steps
  const int dir = blockIdx.z;
  const int tid = threadIdx.x;
  const int l = tid & 63, w = tid >> 6;      // 4 waves
  const int m = l & 15, q = l >> 4;
  const int rowb = rt * 64 + w * 16;         // this wave's 16 rows

  const float* __restrict__ bi = dir ? bib : bif;
  const float* __restrict__ bh = dir ? bhb : bhf;

  // A fragments (W rows) loaded ONCE, reused across TPB time-steps
  bf16x8 ahi[10], alo[10];
  {
    const unsigned short* whi =
        wp + ((size_t)(dir * 2 + 0) * 2048 + rowb + m) * EP_ + q * 8;
    const unsigned short* wlo =
        wp + ((size_t)(dir * 2 + 1) * 2048 + rowb + m) * EP_ + q * 8;
    #pragma unroll
    for (int kt = 0; kt < 10; ++kt) {
      ahi[kt] = *(const bf16x8*)(whi + kt * 32);
      alo[kt] = *(const bf16x8*)(wlo + kt * 32);
    }
  }

  const int r4 = rowb + q * 4;
  const float4 bi4 = *(const float4*)(bi + r4);
  const float4 bh4 = *(const float4*)(bh + r4);
  const float bias0 = bi4.x + bh4.x, bias1 = bi4.y + bh4.y;
  const float bias2 = bi4.z + bh4.z, bias3 = bi4.w + bh4.w;

  const size_t plane = (size_t)T_ * B_ * EP_;

  #pragma unroll
  for (int j = 0; j < TPB; ++j) {
    const int t = tg * TPB + j;
    const unsigned short* xh0 = xb + ((size_t)t * B_ + m     ) * EP_ + q * 8;
    const unsigned short* xh1 = xb + ((size_t)t * B_ + m + 16) * EP_ + q * 8;

    f32x4 acc0 = {0.f, 0.f, 0.f, 0.f}, acc1 = {0.f, 0.f, 0.f, 0.f};
    #pragma unroll
    for (int kt = 0; kt < 10; ++kt) {
      bf16x8 b0h = *(const bf16x8*)(xh0 + kt * 32);
      bf16x8 b0l = *(const bf16x8*)(xh0 + plane + kt * 32);
      bf16x8 b1h = *(const bf16x8*)(xh1 + kt * 32);
      bf16x8 b1l = *(const bf16x8*)(xh1 + plane + kt * 32);
      acc0 = __builtin_amdgcn_mfma_f32_16x16x32_bf16(ahi[kt], b0h, acc0, 0, 0, 0);
      acc0 = __builtin_amdgcn_mfma_f32_16x16x32_bf16(alo[kt], b0h, acc0, 0, 0, 0);
      acc0 = __builtin_amdgcn_mfma_f32_16x16x32_bf16(ahi[kt], b0l, acc0, 0, 0, 0);
      acc1 = __builtin_amdgcn_mfma_f32_16x16x32_bf16(ahi[kt], b1h, acc1, 0, 0, 0);
      acc1 = __builtin_amdgcn_mfma_f32_16x16x32_bf16(alo[kt], b1h, acc1, 0, 0, 0);
      acc1 = __builtin_amdgcn_mfma_f32_16x16x32_bf16(ahi[kt], b1l, acc1, 0, 0, 0);
    }

    unsigned short* og =
        (unsigned short*)xg + ((size_t)(dir * T_ + t) * 2048 + r4) * B_;
    og[0 * B_ + m]      = (unsigned short)f2bf(acc0[0] + bias0);
    og[1 * B_ + m]      = (unsigned short)f2bf(acc0[1] + bias1);
    og[2 * B_ + m]      = (unsigned short)f2bf(acc0[2] + bias2);
    og[3 * B_ + m]      = (unsigned short)f2bf(acc0[3] + bias3);
    og[0 * B_ + m + 16] = (unsigned short)f2bf(acc1[0] + bias0);
    og[1 * B_ + m + 16] = (unsigned short)f2bf(acc1[1] + bias1);
    og[2 * B_ + m + 16] = (unsigned short)f2bf(acc1[2] + bias2);
    og[3 * B_ + m + 16] = (unsigned short)f2bf(acc1[3] + bias3);
  }
}

// ---------------- kernel 2: XCD-local MFMA LSTM recurrence (r16, byte-identical) --
__device__ __forceinline__ float sigm(float x)    { return 1.f / (1.f + __expf(-x)); }
__device__ __forceinline__ float tanhfast(float x){ return 1.f - 2.f / (__expf(2.f * x) + 1.f); }

__global__ __launch_bounds__(THR) void lstm_rec_k(
    const __hip_bfloat16* __restrict__ xg,
    const float* __restrict__ Whf, const float* __restrict__ Whb,
    unsigned short* __restrict__ ht,   // [dir][s][rank 32][plane 2][512] ushort
    float* __restrict__ pooled,
    unsigned int* __restrict__ tags, unsigned int* __restrict__ elect)
{
  unsigned xcd;
  asm volatile("s_getreg_b32 %0, hwreg(HW_REG_XCC_ID)" : "=s"(xcd));
  xcd &= 7u;

  __shared__ unsigned rank_s;
  if (threadIdx.x == 0)
    rank_s = __hip_atomic_fetch_add(&elect[xcd], 1u, __ATOMIC_RELAXED,
                                    __HIP_MEMORY_SCOPE_AGENT);
  __syncthreads();
  const unsigned rank = rank_s;
  if (xcd > 1u || rank >= TEAM) return;   // block-uniform exit (frees CU)
  const int dir = (int)xcd;

  const float* __restrict__ Wh = dir ? Whb : Whf;   // [2048][512]
  const int hs  = (int)rank * HPB;
  const int tid = threadIdx.x;
  const int l   = tid & 63;            // MFMA lane
  const int wid = tid >> 6;            // 8 waves
  const int g   = wid & 3;             // gate (i,f,g,o)
  const int kh  = wid >> 2;            // k-half (0: k<256, 1: k>=256)
  const int hh  = tid & 15, bb = tid >> 4;   // cell-update role (h idx, batch)

  extern __shared__ char lds[];        // [0,64K): h bf16 hi|lo ; [64K,+17408): gp
  float* gp = (float*)(lds + 65536);   // [8 slot][32 b][17] fp32 gate partials

  // ---- A-fragment preload: this wave's 16 W rows x its 256-k half, bf16 hi/lo ---
  bf16x8 ahi[8], alo[8];
  {
    const int m = l & 15, q = l >> 4;
    const float* wrow = Wh + (size_t)(g * H_ + hs + m) * H_ + kh * 256 + q * 8;
    #pragma unroll
    for (int kt = 0; kt < 8; ++kt) {
      const float* wp = wrow + kt * 32;
      #pragma unroll
      for (int j = 0; j < 8; ++j) {
        const float w = wp[j];
        const short hi = f2bf(w);
        ahi[kt][j] = hi;
        alo[kt][j] = f2bf(w - bf2f((unsigned short)hi));
      }
    }
  }

  const unsigned short* __restrict__ xgu = (const unsigned short*)xg;
  const size_t xco = ((size_t)hs + hh) * B_ + bb;   // cell xg offset (per gate +512*32)
  unsigned int* __restrict__ mytags = tags + dir * 32;

  float c_st = 0.f, pm = 0.f;

  for (int s = 0; s < T_; ++s) {
    if (s > 0) {
      // barrier v4 wait: 32 lanes poll the HOT tag line (nt = no L1 allocate);
      // tag >= s means that rank published step s-1. Agent-load backstop.
      if (tid < 64) {
        unsigned v = 0xFFFFFFFFu;
        const unsigned int* tp = mytags + (tid & 31);
        int it = 0;
        do {
          if (tid < 32) {
            if (it < 64) {
              asm volatile("global_load_dword %0, %1, off sc0 nt\n\ts_waitcnt vmcnt(0)"
                           : "=v"(v) : "v"(tp) : "memory");
            } else {
              v = __hip_atomic_load(tp, __ATOMIC_RELAXED, __HIP_MEMORY_SCOPE_AGENT);
            }
          }
          ++it;
        } while (__ballot(v < (unsigned)s) != 0ull && it < (1 << 22));
      }
      __syncthreads();
    }

    // xg prefetch AFTER the poll: latency hides under stage+MFMA, and the
    // poll's per-iteration vmcnt(0) no longer serializes on it.
    const int tt = dir ? (T_ - 1 - s) : s;
    const size_t xb = (size_t)(dir * T_ + tt) * 2048 * B_;
    float x0 = bf2f(__builtin_nontemporal_load(xgu + xb + 0 * H_ * B_ + xco));
    float x1 = bf2f(__builtin_nontemporal_load(xgu + xb + 1 * H_ * B_ + xco));
    float x2 = bf2f(__builtin_nontemporal_load(xgu + xb + 2 * H_ * B_ + xco));
    float x3 = bf2f(__builtin_nontemporal_load(xgu + xb + 3 * H_ * B_ + xco));

    if (s > 0) {
      // stage h(s-1): read 64 KB rank-major linearly, permute into swizzled LDS
      {
        const float4* src = (const float4*)(ht + (size_t)(dir * T_ + (s - 1)) * 32768);
        #pragma unroll
        for (int ii = 0; ii < 8; ++ii) {
          const int i = tid + ii * THR;          // 0..4095
          const float4 v4 = src[i];
          const int rk = i >> 7;                 // rank
          const int f  = i & 127;
          const int pl = f >> 6;                 // plane (hi/lo)
          const int j  = f & 63;                 // float4 within plane
          const int b  = j >> 1;
          const int h0 = (j & 1) * 8;            // first of 8 hh
          const int dst = pl * 32768 +
              ((b * 1024 + (rk * HPB + h0) * 2) ^ ((b & 7) << 4));
          *(float4*)(lds + dst) = v4;
        }
      }
      __syncthreads();
      // MFMA: gates[g*16+hs.. ][b] partial over this k-half
      f32x4 acc0 = {0.f, 0.f, 0.f, 0.f}, acc1 = {0.f, 0.f, 0.f, 0.f};
      {
        const int n0 = l & 15;
        const int swz = (n0 & 7) << 4;
        const int kb = kh * 512 + (l >> 4) * 16;   // byte offset of this lane's k
        #pragma unroll
        for (int kt = 0; kt < 8; ++kt) {
          const int ko = kb + kt * 64;
          const char* p0 = lds + (((n0      ) * 1024 + ko) ^ swz);
          const char* p1 = lds + (((n0 + 16 ) * 1024 + ko) ^ swz);
          bf16x8 b0h = *(const bf16x8*)(p0);
          bf16x8 b0l = *(const bf16x8*)(p0 + 32768);
          bf16x8 b1h = *(const bf16x8*)(p1);
          bf16x8 b1l = *(const bf16x8*)(p1 + 32768);
          acc0 = __builtin_amdgcn_mfma_f32_16x16x32_bf16(ahi[kt], b0h, acc0, 0, 0, 0);
          acc0 = __builtin_amdgcn_mfma_f32_16x16x32_bf16(alo[kt], b0h, acc0, 0, 0, 0);
          acc0 = __builtin_amdgcn_mfma_f32_16x16x32_bf16(ahi[kt], b0l, acc0, 0, 0, 0);
          acc1 = __builtin_amdgcn_mfma_f32_16x16x32_bf16(ahi[kt], b1h, acc1, 0, 0, 0);
          acc1 = __builtin_amdgcn_mfma_f32_16x16x32_bf16(alo[kt], b1h, acc1, 0, 0, 0);
          acc1 = __builtin_amdgcn_mfma_f32_16x16x32_bf16(ahi[kt], b1l, acc1, 0, 0, 0);
        }
      }
      // write gate partials: C layout col=lane&15 (batch), row=(lane>>4)*4+r (h)
      {
        const int slot = (kh * 4 + g) * 32;
        const int rowb = (l >> 4) * 4;
        #pragma unroll
        for (int r = 0; r < 4; ++r) {
          gp[(slot + (l & 15)     ) * 17 + rowb + r] = acc0[r];
          gp[(slot + 16 + (l & 15)) * 17 + rowb + r] = acc1[r];
        }
      }
      __syncthreads();
    }

    // ---- cell update for (h = hs+hh, batch bb) ----
    float Gi = x0, Gf = x1, Gg = x2, Go = x3;
    if (s > 0) {
      Gi += gp[(0 * 32 + bb) * 17 + hh] + gp[(4 * 32 + bb) * 17 + hh];
      Gf += gp[(1 * 32 + bb) * 17 + hh] + gp[(5 * 32 + bb) * 17 + hh];
      Gg += gp[(2 * 32 + bb) * 17 + hh] + gp[(6 * 32 + bb) * 17 + hh];
      Go += gp[(3 * 32 + bb) * 17 + hh] + gp[(7 * 32 + bb) * 17 + hh];
    }
    c_st = sigm(Gf) * c_st + sigm(Gi) * tanhfast(Gg);
    const float h = sigm(Go) * tanhfast(c_st);
    pm = fmaxf(pm, h);
    // publish h: CONTIGUOUS rank-major region; region[tid] -> each wave64
    // writes one full 128B line (hi) + one (lo). No sub-line merge fetch.
    {
      const short hi = f2bf(h);
      const short lo = f2bf(h - bf2f((unsigned short)hi));
      unsigned short* region =
          ht + (size_t)(dir * T_ + s) * 32768 + (size_t)rank * 1024;
      region[tid]       = (unsigned short)hi;
      region[512 + tid] = (unsigned short)lo;
    }
    // drain own stores to local L2, block-wide, then arrive: monotonic tag
    // store into the permanently-hot per-direction control line.
    asm volatile("s_waitcnt vmcnt(0)" ::: "memory");
    __syncthreads();
    if (tid == 0) {
      unsigned int* tp = mytags + rank;
      unsigned val = (unsigned)(s + 1);
      asm volatile("global_store_dword %0, %1, off\n\ts_waitcnt vmcnt(0)"
                   :: "v"(tp), "v"(val) : "memory");
    }
  }
  pooled[(size_t)bb * 1024 + dir * H_ + hs + hh] = pm;
}

// ---------------- kernel 3: ht v2 -> rnn_out [t][b][dir*512+k] fp32 ---------------
__global__ __launch_bounds__(256) void finalize_k(
    const unsigned short* __restrict__ ht, float* __restrict__ rnn)
{
  const int t = blockIdx.x, dir = blockIdx.y;
  const int s = dir ? (T_ - 1 - t) : t;
  const unsigned short* slab = ht + (size_t)(dir * T_ + s) * 32768;
  const int b = threadIdx.x >> 3, c = threadIdx.x & 7;
  float* __restrict__ dst = rnn + ((size_t)t * B_ + b) * 1024 + dir * H_;
  #pragma unroll
  for (int j = 0; j < 16; ++j) {
    const int k0 = c * 64 + j * 4;                 // 4 consecutive k, same rank
    const int rk = k0 >> 4;
    const unsigned short* rg = slab + rk * 1024 + b * HPB + (k0 & 15);
    float4 o;
    o.x = bf2f(rg[0]) + bf2f(rg[512 + 0]);
    o.y = bf2f(rg[1]) + bf2f(rg[512 + 1]);
    o.z = bf2f(rg[2]) + bf2f(rg[512 + 2]);
    o.w = bf2f(rg[3]) + bf2f(rg[512 + 3]);
    *(float4*)(dst + k0) = o;
  }
}

// ---------------- kernel 4: logits = pooled @ W_out^T + b_out ---------------------
__global__ __launch_bounds__(64) void logits_k(
    const float* __restrict__ pooled, const float* __restrict__ Wout,
    const float* __restrict__ bout, float* __restrict__ out)
{
  const int b = blockIdx.x, lane = threadIdx.x;
  float acc[O_];
  #pragma unroll
  for (int o = 0; o < O_; ++o) acc[o] = 0.f;
  for (int k = lane; k < 2 * H_; k += 64) {
    const float pv = pooled[(size_t)b * 1024 + k];
    #pragma unroll
    for (int o = 0; o < O_; ++o) acc[o] += pv * Wout[(size_t)o * 1024 + k];
  }
  #pragma unroll
  for (int o = 0; o < O_; ++o) {
    float v = acc[o];
    #pragma unroll
    for (int off = 32; off > 0; off >>= 1) v += __shfl_down(v, off);
    if (lane == 0) out[b * O_ + o] = v + bout[o];
  }
}

extern "C" void kernel_launch(void* const* d_in, const int* in_sizes, int n_in,
                              void* d_out, int out_size, void* d_ws, size_t ws_size,
                              hipStream_t stream)
{
  const int*   tokens = (const int*)d_in[0];
  const float* embed  = (const float*)d_in[1];
  const float* Wihf   = (const float*)d_in[2];
  const float* Whhf   = (const float*)d_in[3];
  const float* bihf   = (const float*)d_in[4];
  const float* bhhf   = (const float*)d_in[5];
  const float* Wihb   = (const float*)d_in[6];
  const float* Whhb   = (const float*)d_in[7];
  const float* bihb   = (const float*)d_in[8];
  const float* bhhb   = (const float*)d_in[9];
  const float* Wout   = (const float*)d_in[10];
  const float* bout   = (const float*)d_in[11];
  float* out = (float*)d_out;

  char* ws = (char*)d_ws;
  const size_t XG_BYTES = (size_t)2 * T_ * 2048 * B_ * 2;       // 67,108,864
  const size_t HT_BYTES = (size_t)2 * T_ * 32768 * 2;           // 33,554,432
  const size_t PL_BYTES = (size_t)B_ * 1024 * 4;                //    131,072
  const size_t TG_BYTES = 2 * 32 * 4;                           //        256
  const size_t EL_BYTES = 8 * 4;                                //         32
  if (ws_size < XG_BYTES + HT_BYTES + PL_BYTES + TG_BYTES + EL_BYTES) return;

  __hip_bfloat16* xg     = (__hip_bfloat16*)ws;
  unsigned short* ht     = (unsigned short*)(ws + XG_BYTES);
  float*          pooled = (float*)(ws + XG_BYTES + HT_BYTES);
  unsigned int*   tags   = (unsigned int*)(ws + XG_BYTES + HT_BYTES + PL_BYTES);
  unsigned int*   elect  = (unsigned int*)(ws + XG_BYTES + HT_BYTES + PL_BYTES + TG_BYTES);

  // xb (10,485,760 B) and wp (5,242,880 B) ALIAS the ht region: fully consumed
  // by xg_mfma_k before lstm writes ht (stream-ordered).
  unsigned short* xb = (unsigned short*)(ws + XG_BYTES);
  unsigned short* wpre = (unsigned short*)(ws + XG_BYTES + (size_t)2 * T_ * B_ * EP_ * 2);

  (void)hipMemsetAsync(tags, 0, TG_BYTES + EL_BYTES, stream);

  xprep_k<<<dim3(T_), 256, 0, stream>>>(tokens, embed, xb);
  wprep_k<<<dim3(2048, 2), 320, 0, stream>>>(Wihf, Wihb, wpre);
  xg_mfma_k<<<dim3(32, T_ / TPB, 2), 256, 0, stream>>>(wpre, xb, bihf, bhhf,
                                                       bihb, bhhb, xg);

  // 82,944 B dynamic LDS (64K h + 17,408 gp); 2x82944 > 160 KB -> 1 block/CU.
  const int rec_lds = 82944;
  (void)hipFuncSetAttribute((const void*)lstm_rec_k,
                            hipFuncAttributeMaxDynamicSharedMemorySize, rec_lds);
  lstm_rec_k<<<dim3(NBLK), THR, rec_lds, stream>>>(xg, Whhf, Whhb, ht, pooled,
                                                   tags, elect);

  finalize_k<<<dim3(T_, 2), 256, 0, stream>>>(ht, out + B_ * O_);
  logits_k<<<dim3(B_), 64, 0, stream>>>(pooled, Wout, bout, out);
}